// Round 10
// baseline (233.676 us; speedup 1.0000x reference)
//
#include <hip/hip_runtime.h>
#include <hip/hip_bf16.h>

typedef __hip_bfloat16 bf16;
__device__ __forceinline__ float bf2f(bf16 v) { return __bfloat162float(v); }

typedef __attribute__((ext_vector_type(8))) short short8;
typedef __attribute__((ext_vector_type(4))) float floatx4;

#define EB_BITS 8            // 256 edge segments per bucket  (~12.8k recs)
#define VB_BITS 10           // 1024 vertex segments per bucket (~10.2k recs)
#define MAXBK   256          // bucket count ceiling (here 79+98=177)
#define F1_ITEMS 4096        // incidences per bucketize block -> 8192 records

__device__ __forceinline__ int rbase(int b, int nEB, int capE, int capV) {
  return (b < nEB) ? b * capE : nEB * capE + (b - nEB) * capV;
}

// ===========================================================================
// Init per-bucket write cursors to region bases.
// ===========================================================================
__global__ void init_cursor_kernel(int* __restrict__ gcursor, int KB,
                                   int nEB, int capE, int capV) {
  const int b = threadIdx.x;
  if (b < KB) gcursor[b] = rbase(b, nEB, capE, capV);
}

// ===========================================================================
// F1: bucketize incidences into per-bucket regions with DENSE writes.
// Record = (key_local:10 | val:17). LDS staging -> coalesced runs.
// ===========================================================================
__global__ __launch_bounds__(256) void bucketize_kernel(
    const int* __restrict__ vertex, const int* __restrict__ edges,
    int* __restrict__ gcursor, int* __restrict__ records,
    int nnz, int E, int KB, int nEB, int capE, int capV) {
  __shared__ int cnt[MAXBK];
  __shared__ int scanEx[MAXBK];
  __shared__ int bases[MAXBK];
  __shared__ int staged[2 * F1_ITEMS];
  __shared__ unsigned char sbkt[2 * F1_ITEMS];

  const int tid    = threadIdx.x;
  const int base   = blockIdx.x * F1_ITEMS;
  const int iEnd   = min(nnz, base + F1_ITEMS);
  const int nitems = iEnd - base;

  cnt[tid] = 0;
  __syncthreads();

  int recs[32];
  int bks[32];
  int nmy = 0;
#pragma unroll
  for (int j = 0; j < 16; ++j) {
    const int i = base + tid + j * 256;
    if (i < iEnd) {
      const int e = __builtin_nontemporal_load(&edges[i]);
      const int v = __builtin_nontemporal_load(&vertex[i]);
      const int bkE = e >> EB_BITS;
      recs[nmy] = ((e & ((1 << EB_BITS) - 1)) << 17) | v;  bks[nmy] = bkE;  ++nmy;
      const int bkV = nEB + (v >> VB_BITS);
      recs[nmy] = ((v & ((1 << VB_BITS) - 1)) << 17) | e;  bks[nmy] = bkV;  ++nmy;
      atomicAdd(&cnt[bkE], 1);
      atomicAdd(&cnt[bkV], 1);
    }
  }
  __syncthreads();

  // Inclusive Hillis-Steele over 256 buckets
  scanEx[tid] = cnt[tid];
  __syncthreads();
  for (int off = 1; off < MAXBK; off <<= 1) {
    int val = (tid >= off) ? scanEx[tid - off] : 0;
    __syncthreads();
    scanEx[tid] += val;
    __syncthreads();
  }
  // Reserve global runs; convert scan to exclusive
  if (tid < KB && cnt[tid] > 0) bases[tid] = atomicAdd(&gcursor[tid], cnt[tid]);
  scanEx[tid] -= cnt[tid];
  __syncthreads();
  cnt[tid] = 0;
  __syncthreads();

  // Stage records grouped by bucket
  for (int r = 0; r < nmy; ++r) {
    const int b = bks[r];
    const int p = atomicAdd(&cnt[b], 1);
    const int s = scanEx[b] + p;
    staged[s] = recs[r];
    sbkt[s] = (unsigned char)b;
  }
  __syncthreads();

  // Coalesced copy-out
  const int nrec = 2 * nitems;
  for (int s = tid; s < nrec; s += 256) {
    const int b = sbkt[s];
    records[bases[b] + (s - scanEx[b])] = staged[s];
  }
}

// ===========================================================================
// F2 (fused): per-bucket LDS histogram + local scan + fill.
// perm lives in the SAME fixed per-bucket regions as records, so no
// cross-bucket scan is needed: offs[seg] = absolute perm offset,
// cnts[seg] = segment length. Second records read is L2-hot.
// ===========================================================================
__global__ __launch_bounds__(256) void csr_bucket_kernel(
    const int* __restrict__ records, const int* __restrict__ gcursor,
    int* __restrict__ offs, int* __restrict__ cnts, int* __restrict__ perm,
    int nEB, int capE, int capV, int E, int M) {
  __shared__ int cnt[1 << VB_BITS];
  __shared__ int part[256];
  const int b   = blockIdx.x;
  const int tid = threadIdx.x;

  const int base = rbase(b, nEB, capE, capV);
  const int end  = gcursor[b];

#pragma unroll
  for (int j = 0; j < 4; ++j) cnt[tid * 4 + j] = 0;
  __syncthreads();

  for (int r = base + tid; r < end; r += 256)
    atomicAdd(&cnt[records[r] >> 17], 1);
  __syncthreads();

  // Scan 1024 counters: 4 serial per thread + 256-thread Hillis-Steele
  int c0 = cnt[tid * 4 + 0], c1 = cnt[tid * 4 + 1];
  int c2 = cnt[tid * 4 + 2], c3 = cnt[tid * 4 + 3];
  const int mysum = c0 + c1 + c2 + c3;
  part[tid] = mysum;
  __syncthreads();
  for (int off = 1; off < 256; off <<= 1) {
    int val = (tid >= off) ? part[tid - off] : 0;
    __syncthreads();
    part[tid] += val;
    __syncthreads();
  }
  int run = part[tid] - mysum;   // exclusive prefix for this thread
  __syncthreads();
  cnt[tid * 4 + 0] = base + run;  run += c0;
  cnt[tid * 4 + 1] = base + run;  run += c1;
  cnt[tid * 4 + 2] = base + run;  run += c2;
  cnt[tid * 4 + 3] = base + run;
  __syncthreads();

  int seg_lo, segN;
  if (b < nEB) { seg_lo = b << EB_BITS;               segN = min(E - seg_lo, 1 << EB_BITS); }
  else         { seg_lo = E + ((b - nEB) << VB_BITS); segN = min(M - seg_lo, 1 << VB_BITS); }

  const int cc[4] = {c0, c1, c2, c3};
#pragma unroll
  for (int j = 0; j < 4; ++j) {
    const int k = tid * 4 + j;
    if (k < segN) {
      offs[seg_lo + k] = cnt[k];     // absolute perm offset
      cnts[seg_lo + k] = cc[j];      // segment length
    }
  }
  __syncthreads();

  // Fill perm within this bucket's single-writer window (L2 write-merging)
  for (int r = base + tid; r < end; r += 256) {
    const int rec = records[r];
    const int p = atomicAdd(&cnt[rec >> 17], 1);
    perm[p] = rec & 0x1FFFF;
  }
}

// ===========================================================================
// MFMA GEMM v3: Xl[N,64] (bf16) = X[N,128] (f32) @ W[128,64] (f32).
// Block = 4 waves, one 64-row tile. W^T staged once; B-frags in registers.
// A-fragments loaded REGISTER-DIRECT from global (each lane owns its row):
// zero LDS traffic / zero barriers in the tile path.
// A: a[j]=A[m=lane&15][k=quad*8+j]; B: b[j]=B[k=quad*8+j][n=lane&15]
// C/D: col=lane&15, row=quad*4+reg  (verified layouts)
// ===========================================================================
__device__ __forceinline__ unsigned int pack_bf16x2(float lo, float hi) {
  bf16 a = __float2bfloat16(lo);
  bf16 b = __float2bfloat16(hi);
  unsigned short ua = *(unsigned short*)&a;
  unsigned short ub = *(unsigned short*)&b;
  return (unsigned int)ua | ((unsigned int)ub << 16);
}

__device__ __forceinline__ short8 pack_bf16x8(float4 a, float4 b) {
  union { uint4 u; short8 s; } u;
  u.u.x = pack_bf16x2(a.x, a.y);
  u.u.y = pack_bf16x2(a.z, a.w);
  u.u.z = pack_bf16x2(b.x, b.y);
  u.u.w = pack_bf16x2(b.z, b.w);
  return u.s;
}

#define XS_STRIDE 136

__global__ __launch_bounds__(256) void gemm_kernel(
    const float* __restrict__ X, const float* __restrict__ W,
    bf16* __restrict__ Xl, int Nrows) {
  __shared__ unsigned short Ws[64 * XS_STRIDE];   // W^T: [n][k] bf16

  const int tid  = threadIdx.x;
  const int wave = tid >> 6;
  const int lane = tid & 63;
  const int quad = lane >> 4;
  const int l15  = lane & 15;

  // Stage W^T (8192 elements, coalesced f32 reads)
  for (int i = tid; i < 8192; i += 256) {
    const int k = i >> 6, n = i & 63;
    bf16 h = __float2bfloat16(W[i]);
    Ws[n * XS_STRIDE + k] = *(unsigned short*)&h;
  }
  __syncthreads();

  // Hoist B fragments: b[ct][kt] = W[kt*32+quad*8+j][ct*16+l15]
  short8 bfrag[4][4];
#pragma unroll
  for (int ct = 0; ct < 4; ++ct)
#pragma unroll
    for (int kt = 0; kt < 4; ++kt)
      bfrag[ct][kt] = *(const short8*)&Ws[(ct * 16 + l15) * XS_STRIDE + kt * 32 + quad * 8];

  const int row0 = blockIdx.x * 64;
  int row = row0 + wave * 16 + l15;
  if (row >= Nrows) row = Nrows - 1;           // clamp; stores guarded
  const float* __restrict__ src = X + (size_t)row * 128;

  // Register-direct A fragments (each lane loads its own 32 floats)
  short8 afrag[4];
#pragma unroll
  for (int kt = 0; kt < 4; ++kt) {
    const float4 f0 = *(const float4*)(src + kt * 32 + quad * 8);
    const float4 f1 = *(const float4*)(src + kt * 32 + quad * 8 + 4);
    afrag[kt] = pack_bf16x8(f0, f1);
  }

  floatx4 acc[4];
#pragma unroll
  for (int ct = 0; ct < 4; ++ct) {
    acc[ct] = (floatx4){0.f, 0.f, 0.f, 0.f};
#pragma unroll
    for (int kt = 0; kt < 4; ++kt)
      acc[ct] = __builtin_amdgcn_mfma_f32_16x16x32_bf16(
          afrag[kt], bfrag[ct][kt], acc[ct], 0, 0, 0);
  }

  // Store C: row = row0 + wave*16 + quad*4 + reg, col = ct*16 + l15
  const int rb = row0 + wave * 16 + quad * 4;
#pragma unroll
  for (int ct = 0; ct < 4; ++ct) {
    const int col = ct * 16 + l15;
#pragma unroll
    for (int reg = 0; reg < 4; ++reg) {
      const int r = rb + reg;
      if (r < Nrows) Xl[(size_t)r * 64 + col] = __float2bfloat16(acc[ct][reg]);
    }
  }
}

// ===========================================================================
// Gather 1: one wave per hyperedge. Xe[e] = degE[e]*W_edge[e] * sum_v Xl[v]
// ===========================================================================
__global__ __launch_bounds__(256) void gather_e_kernel(
    const bf16* __restrict__ Xl, const int* __restrict__ perm,
    const int* __restrict__ offs, const int* __restrict__ cnts,
    const float* __restrict__ degE, const float* __restrict__ W_edge,
    bf16* __restrict__ Xe, int E) {
  const int gtid = blockIdx.x * 256 + threadIdx.x;
  const int e    = gtid >> 6;
  const int lane = gtid & 63;
  if (e >= E) return;

  const int beg = offs[e];
  const int end = beg + cnts[e];
  float acc = 0.f;

  for (int base = beg; base < end; base += 64) {
    const int n = min(64, end - base);
    const int idx = (lane < n) ? __builtin_nontemporal_load(&perm[base + lane]) : 0;
    int jj = 0;
    for (; jj + 4 <= n; jj += 4) {
      const int v0 = __shfl(idx, jj + 0, 64);
      const int v1 = __shfl(idx, jj + 1, 64);
      const int v2 = __shfl(idx, jj + 2, 64);
      const int v3 = __shfl(idx, jj + 3, 64);
      const float f0 = bf2f(Xl[(size_t)v0 * 64 + lane]);
      const float f1 = bf2f(Xl[(size_t)v1 * 64 + lane]);
      const float f2 = bf2f(Xl[(size_t)v2 * 64 + lane]);
      const float f3 = bf2f(Xl[(size_t)v3 * 64 + lane]);
      acc += (f0 + f1) + (f2 + f3);
    }
    for (; jj < n; ++jj) {
      const int v = __shfl(idx, jj, 64);
      acc += bf2f(Xl[(size_t)v * 64 + lane]);
    }
  }
  const float s = degE[e] * W_edge[e];
  Xe[(size_t)e * 64 + lane] = __float2bfloat16(acc * s);
}

// ===========================================================================
// Gather 2: one wave per node. out[v] = degV[v] * sum_e Xe[e]
// ===========================================================================
__global__ __launch_bounds__(256) void gather_v_kernel(
    const bf16* __restrict__ Xe, const int* __restrict__ perm,
    const int* __restrict__ offs, const int* __restrict__ cnts,
    const float* __restrict__ degV, float* __restrict__ out, int N, int E) {
  const int gtid = blockIdx.x * 256 + threadIdx.x;
  const int v    = gtid >> 6;
  const int lane = gtid & 63;
  if (v >= N) return;

  const int beg = offs[E + v];
  const int end = beg + cnts[E + v];
  float acc = 0.f;

  for (int base = beg; base < end; base += 64) {
    const int n = min(64, end - base);
    const int idx = (lane < n) ? __builtin_nontemporal_load(&perm[base + lane]) : 0;
    int jj = 0;
    for (; jj + 4 <= n; jj += 4) {
      const int e0 = __shfl(idx, jj + 0, 64);
      const int e1 = __shfl(idx, jj + 1, 64);
      const int e2 = __shfl(idx, jj + 2, 64);
      const int e3 = __shfl(idx, jj + 3, 64);
      const float f0 = bf2f(Xe[(size_t)e0 * 64 + lane]);
      const float f1 = bf2f(Xe[(size_t)e1 * 64 + lane]);
      const float f2 = bf2f(Xe[(size_t)e2 * 64 + lane]);
      const float f3 = bf2f(Xe[(size_t)e3 * 64 + lane]);
      acc += (f0 + f1) + (f2 + f3);
    }
    for (; jj < n; ++jj) {
      const int e = __shfl(idx, jj, 64);
      acc += bf2f(Xe[(size_t)e * 64 + lane]);
    }
  }
  __builtin_nontemporal_store(acc * degV[v], &out[(size_t)v * 64 + lane]);
}

// ===========================================================================
extern "C" void kernel_launch(void* const* d_in, const int* in_sizes, int n_in,
                              void* d_out, int out_size, void* d_ws, size_t ws_size,
                              hipStream_t stream) {
  const float* X      = (const float*)d_in[0];
  const int*   vertex = (const int*)d_in[1];
  const int*   edges  = (const int*)d_in[2];
  const float* W      = (const float*)d_in[3];
  const float* degE   = (const float*)d_in[4];
  const float* degV   = (const float*)d_in[5];
  const float* W_edge = (const float*)d_in[6];
  float* out = (float*)d_out;

  const int nnz = in_sizes[1];
  const int E   = in_sizes[4];
  const int N   = in_sizes[5];
  const int M   = E + N;

  const int nEB = (E + (1 << EB_BITS) - 1) >> EB_BITS;
  const int nVB = (N + (1 << VB_BITS) - 1) >> VB_BITS;
  const int KB  = nEB + nVB;

  const int capE = (nnz / nEB) * 3 / 2 + 256;
  const int capV = (nnz / nVB) * 3 / 2 + 256;
  const size_t rec_total = (size_t)nEB * capE + (size_t)nVB * capV;

  // Workspace (~41 MB; ws_size = 256 MiB per harness fill profile)
  char* p = (char*)d_ws;
  auto alloc = [&](size_t bytes) -> void* {
    void* r = (void*)p;
    p += (bytes + 255) & ~(size_t)255;
    return r;
  };
  int*  offs    = (int*)alloc((size_t)(M + 1) * 4);
  int*  cnts    = (int*)alloc((size_t)M * 4);
  int*  gcursor = (int*)alloc(MAXBK * 4);
  int*  records = (int*)alloc(rec_total * 4);
  int*  perm    = (int*)alloc(rec_total * 4);
  bf16* Xl      = (bf16*)alloc((size_t)N * 64 * 2);
  bf16* Xe      = (bf16*)alloc((size_t)E * 64 * 2);

  const int f1blocks = (nnz + F1_ITEMS - 1) / F1_ITEMS;

  init_cursor_kernel<<<1, MAXBK, 0, stream>>>(gcursor, KB, nEB, capE, capV);
  bucketize_kernel<<<f1blocks, 256, 0, stream>>>(vertex, edges, gcursor, records,
                                                 nnz, E, KB, nEB, capE, capV);
  csr_bucket_kernel<<<KB, 256, 0, stream>>>(records, gcursor, offs, cnts, perm,
                                            nEB, capE, capV, E, M);

  gemm_kernel<<<(N + 63) / 64, 256, 0, stream>>>(X, W, Xl, N);

  gather_e_kernel<<<(E + 3) / 4, 256, 0, stream>>>(Xl, perm, offs, cnts, degE, W_edge, Xe, E);
  gather_v_kernel<<<(N + 3) / 4, 256, 0, stream>>>(Xe, perm, offs, cnts, degV, out, N, E);
}